// Round 5
// baseline (558.264 us; speedup 1.0000x reference)
//
#include <hip/hip_runtime.h>
#include <hip/hip_fp16.h>

#define NNODES 50000
#define NEDGES 800000
#define HIDDIM 256
#define EN (NEDGES + NNODES)          // CSR entries incl. self-loops

constexpr float NEG = 0.2f;

typedef __attribute__((ext_vector_type(8))) short short8_t;   // bf16x8 MFMA frag
typedef __attribute__((ext_vector_type(4))) float floatx4;    // f32x4 acc

__device__ __forceinline__ float lrelu(float v){ return v >= 0.f ? v : NEG*v; }

__device__ __forceinline__ unsigned short bf16_rn(float x){
  unsigned u = __float_as_uint(x);
  return (unsigned short)((u + 0x7FFFu + ((u >> 16) & 1u)) >> 16);
}

// ---------------- CSR build (by dst, self-loops included) ----------------
__global__ void k_init_counts(int* counts, int n){
  int i = blockIdx.x*blockDim.x + threadIdx.x;
  if (i < n) counts[i] = 1;
}
__global__ void k_count(const int* __restrict__ ei, int* counts, int E){
  int e = blockIdx.x*blockDim.x + threadIdx.x;
  if (e < E) atomicAdd(&counts[ei[E + e]], 1);
}

#define SCAN_CHUNK 2048
__global__ __launch_bounds__(256) void k_scan_a(const int* __restrict__ counts,
                                                int* __restrict__ bsum, int n){
  __shared__ int ws[4];
  const int t = threadIdx.x;
  const int idx0 = blockIdx.x*SCAN_CHUNK + t*8;
  int s = 0;
  #pragma unroll
  for (int i = 0; i < 8; ++i) if (idx0 + i < n) s += counts[idx0 + i];
  for (int off = 32; off; off >>= 1) s += __shfl_xor(s, off);
  if ((t & 63) == 0) ws[t >> 6] = s;
  __syncthreads();
  if (t == 0) bsum[blockIdx.x] = ws[0] + ws[1] + ws[2] + ws[3];
}
__global__ void k_scan_b(const int* __restrict__ bsum, int* __restrict__ boff,
                         int* __restrict__ offs, int nb, int n){
  if (threadIdx.x == 0){
    int run = 0;
    for (int i = 0; i < nb; ++i){ boff[i] = run; run += bsum[i]; }
    offs[n] = run;
  }
}
__global__ __launch_bounds__(256) void k_scan_c(const int* __restrict__ counts,
                                                const int* __restrict__ boff,
                                                int* __restrict__ offs,
                                                int* __restrict__ cursor, int n){
  __shared__ int sc[256];
  const int t = threadIdx.x;
  const int idx0 = blockIdx.x*SCAN_CHUNK + t*8;
  int v[8], pre[8], s = 0;
  #pragma unroll
  for (int i = 0; i < 8; ++i){
    v[i] = (idx0 + i < n) ? counts[idx0 + i] : 0;
    pre[i] = s; s += v[i];
  }
  sc[t] = s;
  __syncthreads();
  int run = s;
  for (int off = 1; off < 256; off <<= 1){
    int add = (t >= off) ? sc[t - off] : 0;
    __syncthreads();
    sc[t] += add;
    __syncthreads();
  }
  const int excl = sc[t] - run;
  const int toff = boff[blockIdx.x] + excl;
  #pragma unroll
  for (int i = 0; i < 8; ++i){
    if (idx0 + i < n){
      const int o = toff + pre[i];
      offs[idx0 + i] = o;
      cursor[idx0 + i] = o;
    }
  }
}
__global__ void k_scatter(const int* __restrict__ ei, int* cursor,
                          int* __restrict__ esrc, int E, int n){
  int e = blockIdx.x*blockDim.x + threadIdx.x;
  if (e < E){
    int s = ei[e], d = ei[E+e];
    esrc[atomicAdd(&cursor[d], 1)] = s;
  } else if (e < E + n){
    int i = e - E;
    esrc[atomicAdd(&cursor[i], 1)] = i;
  }
}

// ---------------- W split: fp32 -> bf16 hi/lo, fragment-permuted layout ----
__global__ void k_splitW(const float* __restrict__ W, unsigned short* __restrict__ hi,
                         unsigned short* __restrict__ lo, int K){
  int idx = blockIdx.x*256 + threadIdx.x;
  if (idx >= K*HIDDIM) return;
  int k = idx / HIDDIM, n = idx % HIDDIM;
  float w = W[idx];
  unsigned short h = bf16_rn(w);
  float hf = __uint_as_float((unsigned)h << 16);
  unsigned short l = bf16_rn(w - hf);
  int p = ((k >> 3)*HIDDIM + n)*8 + (k & 7);
  hi[p] = h; lo[p] = l;
}

// ---------------- MFMA GEMM + fused logits; h stored channel-blocked fp16 ----
// h16 layout: [chblk=ch>>6][node][ch&63]   (chblk slab = N*64 halfs = 6.4 MB)
template<int K, int NH>
__global__ __launch_bounds__(256) void k_gemm_mfma(
    const float* __restrict__ A,
    const unsigned short* __restrict__ Bhi, const unsigned short* __restrict__ Blo,
    const float* __restrict__ aS, const float* __restrict__ aD,
    __half* __restrict__ Hout, float* __restrict__ as_o, float* __restrict__ ad_o, int M)
{
  constexpr int LDSK = K + 8;
  __shared__ unsigned short sAhi[64*LDSK];
  __shared__ unsigned short sAlo[64*LDSK];
  __shared__ float lred_s[64][4], lred_d[64][4];
  const int tid = threadIdx.x;
  const int row0 = blockIdx.x*64;

  constexpr int CH = 64*K/4/256;
  #pragma unroll
  for (int c = 0; c < CH; ++c){
    const int chunk = c*256 + tid;
    const int r = chunk/(K/4), ko = (chunk%(K/4))*4;
    const int gr = min(row0 + r, M-1);
    const float4 v = *reinterpret_cast<const float4*>(A + (size_t)gr*K + ko);
    ushort4 h, l;
    h.x = bf16_rn(v.x); l.x = bf16_rn(v.x - __uint_as_float((unsigned)h.x<<16));
    h.y = bf16_rn(v.y); l.y = bf16_rn(v.y - __uint_as_float((unsigned)h.y<<16));
    h.z = bf16_rn(v.z); l.z = bf16_rn(v.z - __uint_as_float((unsigned)h.z<<16));
    h.w = bf16_rn(v.w); l.w = bf16_rn(v.w - __uint_as_float((unsigned)h.w<<16));
    *reinterpret_cast<ushort4*>(&sAhi[r*LDSK + ko]) = h;
    *reinterpret_cast<ushort4*>(&sAlo[r*LDSK + ko]) = l;
  }
  __syncthreads();

  const int w = tid >> 6, l = tid & 63;
  const int lr = l & 15, lg = l >> 4;
  const int n0 = w*64;
  floatx4 acc[4][4] = {};

  for (int ks = 0; ks < K/32; ++ks){
    short8_t ah[4], al[4], bh[4], bl[4];
    #pragma unroll
    for (int m = 0; m < 4; ++m){
      const int off = (16*m + lr)*LDSK + ks*32 + lg*8;
      ah[m] = *reinterpret_cast<const short8_t*>(&sAhi[off]);
      al[m] = *reinterpret_cast<const short8_t*>(&sAlo[off]);
    }
    #pragma unroll
    for (int n = 0; n < 4; ++n){
      const int boff = (((ks*4 + lg)*HIDDIM) + n0 + 16*n + lr)*8;
      bh[n] = *reinterpret_cast<const short8_t*>(&Bhi[boff]);
      bl[n] = *reinterpret_cast<const short8_t*>(&Blo[boff]);
    }
    #pragma unroll
    for (int m = 0; m < 4; ++m)
      #pragma unroll
      for (int n = 0; n < 4; ++n){
        acc[m][n] = __builtin_amdgcn_mfma_f32_16x16x32_bf16(ah[m], bh[n], acc[m][n], 0,0,0);
        acc[m][n] = __builtin_amdgcn_mfma_f32_16x16x32_bf16(ah[m], bl[n], acc[m][n], 0,0,0);
        acc[m][n] = __builtin_amdgcn_mfma_f32_16x16x32_bf16(al[m], bh[n], acc[m][n], 0,0,0);
      }
  }

  // h store: chblk = w (since ch = 64w + 16n + lr, 16n+lr < 64)
  __half* slab = Hout + (size_t)w*M*64;
  #pragma unroll
  for (int m = 0; m < 4; ++m){
    #pragma unroll
    for (int r = 0; r < 4; ++r){
      const int row = row0 + 16*m + lg*4 + r;
      if (row < M){
        #pragma unroll
        for (int n = 0; n < 4; ++n)
          slab[(size_t)row*64 + 16*n + lr] = __float2half(acc[m][n][r]);
      }
    }
  }

  float asv[4], adv_[4];
  #pragma unroll
  for (int n = 0; n < 4; ++n){ asv[n] = aS[n0+16*n+lr]; adv_[n] = aD[n0+16*n+lr]; }
  #pragma unroll
  for (int m = 0; m < 4; ++m){
    #pragma unroll
    for (int r = 0; r < 4; ++r){
      float ps = 0.f, pd = 0.f;
      #pragma unroll
      for (int n = 0; n < 4; ++n){
        ps = fmaf(acc[m][n][r], asv[n], ps);
        pd = fmaf(acc[m][n][r], adv_[n], pd);
      }
      #pragma unroll
      for (int off = 1; off <= 8; off <<= 1){
        ps += __shfl_xor(ps, off);
        pd += __shfl_xor(pd, off);
      }
      const int rloc = 16*m + lg*4 + r;
      if (NH == 4){
        if (lr == 0 && row0 + rloc < M){
          as_o[(row0+rloc)*4 + w] = ps;
          ad_o[(row0+rloc)*4 + w] = pd;
        }
      } else {
        if (lr == 0){ lred_s[rloc][w] = ps; lred_d[rloc][w] = pd; }
      }
    }
  }
  if (NH == 1){
    __syncthreads();
    if (tid < 64 && row0 + tid < M){
      float a = lred_s[tid][0]+lred_s[tid][1]+lred_s[tid][2]+lred_s[tid][3];
      float b = lred_d[tid][0]+lred_d[tid][1]+lred_d[tid][2]+lred_d[tid][3];
      as_o[row0+tid] = a; ad_o[row0+tid] = b;
    }
  }
}

// ---------------- k_prep: softmax stats + normalized edge weights (fp16) ----
// one wave per dst node; p16 layout: [head][EN] so chblk reads stay XCD-local
template<int NH>
__global__ __launch_bounds__(256) void k_prep(
    const float* __restrict__ as_, const float* __restrict__ ad_,
    const int* __restrict__ offs, const int* __restrict__ esrc,
    __half* __restrict__ p16, int n)
{
  const int lane = threadIdx.x & 63;
  const int node = blockIdx.x*4 + (threadIdx.x >> 6);
  if (node >= n) return;
  const int start = offs[node], end = offs[node+1];

  float adv[NH], m[NH], dsum[NH];
  #pragma unroll
  for (int h = 0; h < NH; ++h){ adv[h] = ad_[node*NH + h]; m[h] = -1e30f; dsum[h] = 0.f; }

  for (int e = start + lane; e < end; e += 64){
    const int s = esrc[e];
    if (NH == 4){
      const float4 av = *reinterpret_cast<const float4*>(as_ + (size_t)s*4);
      const float a[4] = {av.x, av.y, av.z, av.w};
      #pragma unroll
      for (int h = 0; h < 4; ++h){
        const float v = lrelu(a[h] + adv[h]);
        const float mo = m[h], mn = fmaxf(mo, v);
        dsum[h] = dsum[h]*__expf(mo - mn) + __expf(v - mn);
        m[h] = mn;
      }
    } else {
      const float v = lrelu(as_[s] + adv[0]);
      const float mo = m[0], mn = fmaxf(mo, v);
      dsum[0] = dsum[0]*__expf(mo - mn) + __expf(v - mn);
      m[0] = mn;
    }
  }
  #pragma unroll
  for (int h = 0; h < NH; ++h){
    for (int off = 32; off; off >>= 1){
      const float mo = __shfl_xor(m[h], off);
      const float dd = __shfl_xor(dsum[h], off);
      const float mn = fmaxf(m[h], mo);
      dsum[h] = dsum[h]*__expf(m[h] - mn) + dd*__expf(mo - mn);
      m[h] = mn;
    }
  }
  float rd[NH];
  #pragma unroll
  for (int h = 0; h < NH; ++h) rd[h] = 1.f/(dsum[h] + 1e-16f);

  // sweep 2: write normalized weights per CSR position (coalesced per head slab)
  for (int e = start + lane; e < end; e += 64){
    const int s = esrc[e];
    if (NH == 4){
      const float4 av = *reinterpret_cast<const float4*>(as_ + (size_t)s*4);
      const float a[4] = {av.x, av.y, av.z, av.w};
      #pragma unroll
      for (int h = 0; h < 4; ++h){
        const float p = __expf(lrelu(a[h] + adv[h]) - m[h]) * rd[h];
        p16[(size_t)h*EN + e] = __float2half(p);
      }
    } else {
      const float p = __expf(lrelu(as_[s] + adv[0]) - m[0]) * rd[0];
      p16[e] = __float2half(p);
    }
  }
}

// ---------------- k_agg2: channel-sliced aggregate --------------------------
// grid: chunk*4 + chblk; chblk = blockIdx%4 -> XCD-local h slab (round-robin).
// block = 256 thr = 8 half-waves; half-wave = one node x 64 ch (lane: 2 ch).
template<bool HEADED, bool DO_ELU>
__global__ __launch_bounds__(256) void k_agg2(
    const __half* __restrict__ h16, const __half* __restrict__ p16,
    const int* __restrict__ offs, const int* __restrict__ esrc,
    const float* __restrict__ bias, float* __restrict__ Out, int M)
{
  const int chblk = blockIdx.x & 3;
  const int chunk = blockIdx.x >> 2;
  const int g = threadIdx.x >> 5;           // half-wave 0..7
  const int lane2 = threadIdx.x & 31;       // 2 channels per lane
  const int node = chunk*8 + g;
  if (node >= M) return;
  const int start = offs[node], end = offs[node+1];

  const __half* slab = h16 + (size_t)chblk*M*64 + 2*lane2;
  const __half* pp = p16 + (HEADED ? (size_t)chblk*EN : 0);

  float ax = 0.f, ay = 0.f;
  for (int e = start; e < end; ++e){
    const int s = esrc[e];                             // uniform per half-wave
    const float p = __half2float(pp[e]);               // uniform per half-wave
    const float2 hf = __half22float2(*reinterpret_cast<const __half2*>(slab + (size_t)s*64));
    ax = fmaf(p, hf.x, ax);
    ay = fmaf(p, hf.y, ay);
  }
  const int ch = chblk*64 + 2*lane2;
  const float2 bv = *reinterpret_cast<const float2*>(bias + ch);
  ax += bv.x; ay += bv.y;
  if (DO_ELU){
    ax = ax > 0.f ? ax : __expf(ax) - 1.f;
    ay = ay > 0.f ? ay : __expf(ay) - 1.f;
  }
  *reinterpret_cast<float2*>(Out + (size_t)node*HIDDIM + ch) = make_float2(ax, ay);
}

// ---------------- launch ----------------
extern "C" void kernel_launch(void* const* d_in, const int* in_sizes, int n_in,
                              void* d_out, int out_size, void* d_ws, size_t ws_size,
                              hipStream_t stream)
{
  const float* x    = (const float*)d_in[0];
  const int*   ei   = (const int*)  d_in[1];
  const float* W1   = (const float*)d_in[2];
  const float* aS1  = (const float*)d_in[3];
  const float* aD1  = (const float*)d_in[4];
  const float* b1   = (const float*)d_in[5];
  const float* W2   = (const float*)d_in[6];
  const float* aS2  = (const float*)d_in[7];
  const float* aD2  = (const float*)d_in[8];
  const float* b2   = (const float*)d_in[9];
  float* out = (float*)d_out;

  char* ws = (char*)d_ws;
  size_t off = 0;
  auto alloc = [&](size_t bytes){ void* p = ws + off; off += (bytes + 255) & ~255ull; return p; };
  __half* hbuf  = (__half*)alloc((size_t)NNODES*HIDDIM*sizeof(__half)); // 25.6 MB, blocked [4][N][64]
  __half* p16   = (__half*)alloc((size_t)4*EN*sizeof(__half));          // 6.8 MB
  float* as1    = (float*)alloc((size_t)NNODES*4*sizeof(float));
  float* ad1    = (float*)alloc((size_t)NNODES*4*sizeof(float));
  float* as2    = (float*)alloc((size_t)NNODES*sizeof(float));
  float* ad2    = (float*)alloc((size_t)NNODES*sizeof(float));
  unsigned short* W1hi = (unsigned short*)alloc((size_t)128*HIDDIM*sizeof(short));
  unsigned short* W1lo = (unsigned short*)alloc((size_t)128*HIDDIM*sizeof(short));
  unsigned short* W2hi = (unsigned short*)alloc((size_t)256*HIDDIM*sizeof(short));
  unsigned short* W2lo = (unsigned short*)alloc((size_t)256*HIDDIM*sizeof(short));
  int*   counts = (int*)alloc((size_t)NNODES*sizeof(int));
  int*   offs   = (int*)alloc((size_t)(NNODES+1)*sizeof(int));
  int*   cursor = (int*)alloc((size_t)NNODES*sizeof(int));
  int*   bsum   = (int*)alloc(64*sizeof(int));
  int*   boff   = (int*)alloc(64*sizeof(int));
  int*   esrc   = (int*)alloc((size_t)EN*sizeof(int));

  const int nscan = (NNODES + SCAN_CHUNK - 1)/SCAN_CHUNK;   // 25

  // CSR by dst
  k_init_counts<<<(NNODES+255)/256, 256, 0, stream>>>(counts, NNODES);
  k_count     <<<(NEDGES+255)/256, 256, 0, stream>>>(ei, counts, NEDGES);
  k_scan_a    <<<nscan, 256, 0, stream>>>(counts, bsum, NNODES);
  k_scan_b    <<<1, 64, 0, stream>>>(bsum, boff, offs, nscan, NNODES);
  k_scan_c    <<<nscan, 256, 0, stream>>>(counts, boff, offs, cursor, NNODES);
  k_scatter   <<<(EN+255)/256, 256, 0, stream>>>(ei, cursor, esrc, NEDGES, NNODES);

  // weight splits
  k_splitW<<<(128*HIDDIM+255)/256, 256, 0, stream>>>(W1, W1hi, W1lo, 128);
  k_splitW<<<(256*HIDDIM+255)/256, 256, 0, stream>>>(W2, W2hi, W2lo, 256);

  const int gemm_grid = (NNODES + 63)/64;   // 782
  const int agg_grid  = ((NNODES + 7)/8)*4; // 25000

  // layer 1
  k_gemm_mfma<128,4><<<gemm_grid, 256, 0, stream>>>(x, W1hi, W1lo, aS1, aD1, hbuf, as1, ad1, NNODES);
  k_prep<4><<<(NNODES+3)/4, 256, 0, stream>>>(as1, ad1, offs, esrc, p16, NNODES);
  k_agg2<true,true><<<agg_grid, 256, 0, stream>>>(hbuf, p16, offs, esrc, b1, out, NNODES);

  // layer 2
  k_gemm_mfma<256,1><<<gemm_grid, 256, 0, stream>>>(out, W2hi, W2lo, aS2, aD2, hbuf, as2, ad2, NNODES);
  k_prep<1><<<(NNODES+3)/4, 256, 0, stream>>>(as2, ad2, offs, esrc, p16, NNODES);
  k_agg2<false,false><<<agg_grid, 256, 0, stream>>>(hbuf, p16, offs, esrc, b2, out, NNODES);
}

// Round 6
// 351.416 us; speedup vs baseline: 1.5886x; 1.5886x over previous
//
#include <hip/hip_runtime.h>
#include <hip/hip_fp16.h>

#define NNODES 50000
#define NEDGES 800000
#define HIDDIM 256
#define EN (NEDGES + NNODES)          // CSR entries incl. self-loops

constexpr float NEG = 0.2f;

typedef __attribute__((ext_vector_type(8))) short short8_t;   // bf16x8 MFMA frag
typedef __attribute__((ext_vector_type(4))) float floatx4;    // f32x4 acc

__device__ __forceinline__ float lrelu(float v){ return v >= 0.f ? v : NEG*v; }

__device__ __forceinline__ unsigned short bf16_rn(float x){
  unsigned u = __float_as_uint(x);
  return (unsigned short)((u + 0x7FFFu + ((u >> 16) & 1u)) >> 16);
}

__device__ __forceinline__ float4 ldh4(const __half* p){
  union { float2 f; __half2 h[2]; } u;
  u.f = *reinterpret_cast<const float2*>(p);
  const float2 lo = __half22float2(u.h[0]);
  const float2 hi = __half22float2(u.h[1]);
  return make_float4(lo.x, lo.y, hi.x, hi.y);
}

// ---------------- CSR build (by dst, self-loops included) ----------------
__global__ void k_init_counts(int* counts, int n){
  int i = blockIdx.x*blockDim.x + threadIdx.x;
  if (i < n) counts[i] = 1;
}
__global__ void k_count(const int* __restrict__ ei, int* counts, int E){
  int e = blockIdx.x*blockDim.x + threadIdx.x;
  if (e < E) atomicAdd(&counts[ei[E + e]], 1);
}

#define SCAN_CHUNK 2048
__global__ __launch_bounds__(256) void k_scan_a(const int* __restrict__ counts,
                                                int* __restrict__ bsum, int n){
  __shared__ int ws[4];
  const int t = threadIdx.x;
  const int idx0 = blockIdx.x*SCAN_CHUNK + t*8;
  int s = 0;
  #pragma unroll
  for (int i = 0; i < 8; ++i) if (idx0 + i < n) s += counts[idx0 + i];
  for (int off = 32; off; off >>= 1) s += __shfl_xor(s, off);
  if ((t & 63) == 0) ws[t >> 6] = s;
  __syncthreads();
  if (t == 0) bsum[blockIdx.x] = ws[0] + ws[1] + ws[2] + ws[3];
}
__global__ void k_scan_b(const int* __restrict__ bsum, int* __restrict__ boff,
                         int* __restrict__ offs, int nb, int n){
  if (threadIdx.x == 0){
    int run = 0;
    for (int i = 0; i < nb; ++i){ boff[i] = run; run += bsum[i]; }
    offs[n] = run;
  }
}
__global__ __launch_bounds__(256) void k_scan_c(const int* __restrict__ counts,
                                                const int* __restrict__ boff,
                                                int* __restrict__ offs,
                                                int* __restrict__ cursor, int n){
  __shared__ int sc[256];
  const int t = threadIdx.x;
  const int idx0 = blockIdx.x*SCAN_CHUNK + t*8;
  int v[8], pre[8], s = 0;
  #pragma unroll
  for (int i = 0; i < 8; ++i){
    v[i] = (idx0 + i < n) ? counts[idx0 + i] : 0;
    pre[i] = s; s += v[i];
  }
  sc[t] = s;
  __syncthreads();
  int run = s;
  for (int off = 1; off < 256; off <<= 1){
    int add = (t >= off) ? sc[t - off] : 0;
    __syncthreads();
    sc[t] += add;
    __syncthreads();
  }
  const int excl = sc[t] - run;
  const int toff = boff[blockIdx.x] + excl;
  #pragma unroll
  for (int i = 0; i < 8; ++i){
    if (idx0 + i < n){
      const int o = toff + pre[i];
      offs[idx0 + i] = o;
      cursor[idx0 + i] = o;
    }
  }
}
__global__ void k_scatter(const int* __restrict__ ei, int* cursor,
                          int* __restrict__ esrc, int E, int n){
  int e = blockIdx.x*blockDim.x + threadIdx.x;
  if (e < E){
    int s = ei[e], d = ei[E+e];
    esrc[atomicAdd(&cursor[d], 1)] = s;
  } else if (e < E + n){
    int i = e - E;
    esrc[atomicAdd(&cursor[i], 1)] = i;
  }
}

// ---------------- W split: fp32 -> bf16 hi/lo, fragment-permuted layout ----
__global__ void k_splitW(const float* __restrict__ W, unsigned short* __restrict__ hi,
                         unsigned short* __restrict__ lo, int K){
  int idx = blockIdx.x*256 + threadIdx.x;
  if (idx >= K*HIDDIM) return;
  int k = idx / HIDDIM, n = idx % HIDDIM;
  float w = W[idx];
  unsigned short h = bf16_rn(w);
  float hf = __uint_as_float((unsigned)h << 16);
  unsigned short l = bf16_rn(w - hf);
  int p = ((k >> 3)*HIDDIM + n)*8 + (k & 7);
  hi[p] = h; lo[p] = l;
}

// ---------------- MFMA GEMM + fused logits, flat [N][256] fp16 h -----------
template<int K, int NH>
__global__ __launch_bounds__(256) void k_gemm_mfma(
    const float* __restrict__ A,
    const unsigned short* __restrict__ Bhi, const unsigned short* __restrict__ Blo,
    const float* __restrict__ aS, const float* __restrict__ aD,
    __half* __restrict__ Hout, float* __restrict__ as_o, float* __restrict__ ad_o, int M)
{
  constexpr int LDSK = K + 8;
  __shared__ unsigned short sAhi[64*LDSK];
  __shared__ unsigned short sAlo[64*LDSK];
  __shared__ float lred_s[64][4], lred_d[64][4];
  const int tid = threadIdx.x;
  const int row0 = blockIdx.x*64;

  constexpr int CH = 64*K/4/256;
  #pragma unroll
  for (int c = 0; c < CH; ++c){
    const int chunk = c*256 + tid;
    const int r = chunk/(K/4), ko = (chunk%(K/4))*4;
    const int gr = min(row0 + r, M-1);
    const float4 v = *reinterpret_cast<const float4*>(A + (size_t)gr*K + ko);
    ushort4 h, l;
    h.x = bf16_rn(v.x); l.x = bf16_rn(v.x - __uint_as_float((unsigned)h.x<<16));
    h.y = bf16_rn(v.y); l.y = bf16_rn(v.y - __uint_as_float((unsigned)h.y<<16));
    h.z = bf16_rn(v.z); l.z = bf16_rn(v.z - __uint_as_float((unsigned)h.z<<16));
    h.w = bf16_rn(v.w); l.w = bf16_rn(v.w - __uint_as_float((unsigned)h.w<<16));
    *reinterpret_cast<ushort4*>(&sAhi[r*LDSK + ko]) = h;
    *reinterpret_cast<ushort4*>(&sAlo[r*LDSK + ko]) = l;
  }
  __syncthreads();

  const int w = tid >> 6, l = tid & 63;
  const int lr = l & 15, lg = l >> 4;
  const int n0 = w*64;
  floatx4 acc[4][4] = {};

  for (int ks = 0; ks < K/32; ++ks){
    short8_t ah[4], al[4], bh[4], bl[4];
    #pragma unroll
    for (int m = 0; m < 4; ++m){
      const int off = (16*m + lr)*LDSK + ks*32 + lg*8;
      ah[m] = *reinterpret_cast<const short8_t*>(&sAhi[off]);
      al[m] = *reinterpret_cast<const short8_t*>(&sAlo[off]);
    }
    #pragma unroll
    for (int n = 0; n < 4; ++n){
      const int boff = (((ks*4 + lg)*HIDDIM) + n0 + 16*n + lr)*8;
      bh[n] = *reinterpret_cast<const short8_t*>(&Bhi[boff]);
      bl[n] = *reinterpret_cast<const short8_t*>(&Blo[boff]);
    }
    #pragma unroll
    for (int m = 0; m < 4; ++m)
      #pragma unroll
      for (int n = 0; n < 4; ++n){
        acc[m][n] = __builtin_amdgcn_mfma_f32_16x16x32_bf16(ah[m], bh[n], acc[m][n], 0,0,0);
        acc[m][n] = __builtin_amdgcn_mfma_f32_16x16x32_bf16(ah[m], bl[n], acc[m][n], 0,0,0);
        acc[m][n] = __builtin_amdgcn_mfma_f32_16x16x32_bf16(al[m], bh[n], acc[m][n], 0,0,0);
      }
  }

  #pragma unroll
  for (int m = 0; m < 4; ++m){
    #pragma unroll
    for (int r = 0; r < 4; ++r){
      const int row = row0 + 16*m + lg*4 + r;
      if (row < M){
        #pragma unroll
        for (int n = 0; n < 4; ++n)
          Hout[(size_t)row*HIDDIM + n0 + 16*n + lr] = __float2half(acc[m][n][r]);
      }
    }
  }

  float asv[4], adv_[4];
  #pragma unroll
  for (int n = 0; n < 4; ++n){ asv[n] = aS[n0+16*n+lr]; adv_[n] = aD[n0+16*n+lr]; }
  #pragma unroll
  for (int m = 0; m < 4; ++m){
    #pragma unroll
    for (int r = 0; r < 4; ++r){
      float ps = 0.f, pd = 0.f;
      #pragma unroll
      for (int n = 0; n < 4; ++n){
        ps = fmaf(acc[m][n][r], asv[n], ps);
        pd = fmaf(acc[m][n][r], adv_[n], pd);
      }
      #pragma unroll
      for (int off = 1; off <= 8; off <<= 1){
        ps += __shfl_xor(ps, off);
        pd += __shfl_xor(pd, off);
      }
      const int rloc = 16*m + lg*4 + r;
      if (NH == 4){
        if (lr == 0 && row0 + rloc < M){
          as_o[(row0+rloc)*4 + w] = ps;
          ad_o[(row0+rloc)*4 + w] = pd;
        }
      } else {
        if (lr == 0){ lred_s[rloc][w] = ps; lred_d[rloc][w] = pd; }
      }
    }
  }
  if (NH == 1){
    __syncthreads();
    if (tid < 64 && row0 + tid < M){
      float a = lred_s[tid][0]+lred_s[tid][1]+lred_s[tid][2]+lred_s[tid][3];
      float b = lred_d[tid][0]+lred_d[tid][1]+lred_d[tid][2]+lred_d[tid][3];
      as_o[row0+tid] = a; ad_o[row0+tid] = b;
    }
  }
}

// ---------------- k_prep: softmax stats + normalized edge weights (fp16) ----
// one wave per dst node; p16 interleaved [e][NH] (half4 per edge for NH=4)
template<int NH>
__global__ __launch_bounds__(256) void k_prep(
    const float* __restrict__ as_, const float* __restrict__ ad_,
    const int* __restrict__ offs, const int* __restrict__ esrc,
    __half* __restrict__ p16, int n)
{
  const int lane = threadIdx.x & 63;
  const int node = blockIdx.x*4 + (threadIdx.x >> 6);
  if (node >= n) return;
  const int start = offs[node], end = offs[node+1];

  float adv[NH], m[NH], dsum[NH];
  #pragma unroll
  for (int h = 0; h < NH; ++h){ adv[h] = ad_[node*NH + h]; m[h] = -1e30f; dsum[h] = 0.f; }

  for (int e = start + lane; e < end; e += 64){
    const int s = esrc[e];
    if (NH == 4){
      const float4 av = *reinterpret_cast<const float4*>(as_ + (size_t)s*4);
      const float a[4] = {av.x, av.y, av.z, av.w};
      #pragma unroll
      for (int h = 0; h < 4; ++h){
        const float v = lrelu(a[h] + adv[h]);
        const float mo = m[h], mn = fmaxf(mo, v);
        dsum[h] = dsum[h]*__expf(mo - mn) + __expf(v - mn);
        m[h] = mn;
      }
    } else {
      const float v = lrelu(as_[s] + adv[0]);
      const float mo = m[0], mn = fmaxf(mo, v);
      dsum[0] = dsum[0]*__expf(mo - mn) + __expf(v - mn);
      m[0] = mn;
    }
  }
  #pragma unroll
  for (int h = 0; h < NH; ++h){
    for (int off = 32; off; off >>= 1){
      const float mo = __shfl_xor(m[h], off);
      const float dd = __shfl_xor(dsum[h], off);
      const float mn = fmaxf(m[h], mo);
      dsum[h] = dsum[h]*__expf(m[h] - mn) + dd*__expf(mo - mn);
      m[h] = mn;
    }
  }
  float rd[NH];
  #pragma unroll
  for (int h = 0; h < NH; ++h) rd[h] = 1.f/(dsum[h] + 1e-16f);

  // sweep 2: write normalized weights (interleaved per edge)
  for (int e = start + lane; e < end; e += 64){
    const int s = esrc[e];
    if (NH == 4){
      const float4 av = *reinterpret_cast<const float4*>(as_ + (size_t)s*4);
      const float a[4] = {av.x, av.y, av.z, av.w};
      union { float2 f; __half2 h2[2]; } o;
      o.h2[0] = __half2{__float2half(__expf(lrelu(a[0] + adv[0]) - m[0]) * rd[0]),
                        __float2half(__expf(lrelu(a[1] + adv[1]) - m[1]) * rd[1])};
      o.h2[1] = __half2{__float2half(__expf(lrelu(a[2] + adv[2]) - m[2]) * rd[2]),
                        __float2half(__expf(lrelu(a[3] + adv[3]) - m[3]) * rd[3])};
      *reinterpret_cast<float2*>(&p16[(size_t)4*e]) = o.f;
    } else {
      const float p = __expf(lrelu(as_[s] + adv[0]) - m[0]) * rd[0];
      p16[e] = __float2half(p);
    }
  }
}

// ---------------- k_agg3: pure gather-accumulate, 4x unrolled ---------------
// one wave per dst node; lane owns channels [4*lane,4*lane+4); head = lane>>4
template<int NH, bool DO_ELU>
__global__ __launch_bounds__(256) void k_agg3(
    const __half* __restrict__ Hs, const __half* __restrict__ p16,
    const int* __restrict__ offs, const int* __restrict__ esrc,
    const float* __restrict__ bias, float* __restrict__ Out, int n)
{
  const int lane = threadIdx.x & 63;
  const int node = blockIdx.x*4 + (threadIdx.x >> 6);
  if (node >= n) return;
  const int start = offs[node], end = offs[node+1];
  const int head = (NH == 4) ? (lane >> 4) : 0;
  const __half* hp = Hs + 4*lane;

  float4 a0 = {0,0,0,0}, a1 = {0,0,0,0}, a2 = {0,0,0,0}, a3 = {0,0,0,0};
  int e = start;
  for (; e + 4 <= end; e += 4){
    const int s0 = esrc[e+0], s1 = esrc[e+1], s2 = esrc[e+2], s3 = esrc[e+3];
    const float p0 = __half2float(p16[(size_t)NH*(e+0) + head]);
    const float p1 = __half2float(p16[(size_t)NH*(e+1) + head]);
    const float p2 = __half2float(p16[(size_t)NH*(e+2) + head]);
    const float p3 = __half2float(p16[(size_t)NH*(e+3) + head]);
    const float4 h0 = ldh4(hp + (size_t)s0*HIDDIM);
    const float4 h1 = ldh4(hp + (size_t)s1*HIDDIM);
    const float4 h2 = ldh4(hp + (size_t)s2*HIDDIM);
    const float4 h3 = ldh4(hp + (size_t)s3*HIDDIM);
    a0.x = fmaf(p0, h0.x, a0.x); a0.y = fmaf(p0, h0.y, a0.y);
    a0.z = fmaf(p0, h0.z, a0.z); a0.w = fmaf(p0, h0.w, a0.w);
    a1.x = fmaf(p1, h1.x, a1.x); a1.y = fmaf(p1, h1.y, a1.y);
    a1.z = fmaf(p1, h1.z, a1.z); a1.w = fmaf(p1, h1.w, a1.w);
    a2.x = fmaf(p2, h2.x, a2.x); a2.y = fmaf(p2, h2.y, a2.y);
    a2.z = fmaf(p2, h2.z, a2.z); a2.w = fmaf(p2, h2.w, a2.w);
    a3.x = fmaf(p3, h3.x, a3.x); a3.y = fmaf(p3, h3.y, a3.y);
    a3.z = fmaf(p3, h3.z, a3.z); a3.w = fmaf(p3, h3.w, a3.w);
  }
  for (; e < end; ++e){
    const int s = esrc[e];
    const float p = __half2float(p16[(size_t)NH*e + head]);
    const float4 hv = ldh4(hp + (size_t)s*HIDDIM);
    a0.x = fmaf(p, hv.x, a0.x); a0.y = fmaf(p, hv.y, a0.y);
    a0.z = fmaf(p, hv.z, a0.z); a0.w = fmaf(p, hv.w, a0.w);
  }
  float4 acc;
  acc.x = (a0.x + a1.x) + (a2.x + a3.x);
  acc.y = (a0.y + a1.y) + (a2.y + a3.y);
  acc.z = (a0.z + a1.z) + (a2.z + a3.z);
  acc.w = (a0.w + a1.w) + (a2.w + a3.w);

  const float4 bv = *reinterpret_cast<const float4*>(bias + 4*lane);
  acc.x += bv.x; acc.y += bv.y; acc.z += bv.z; acc.w += bv.w;
  if (DO_ELU){
    acc.x = acc.x > 0.f ? acc.x : __expf(acc.x) - 1.f;
    acc.y = acc.y > 0.f ? acc.y : __expf(acc.y) - 1.f;
    acc.z = acc.z > 0.f ? acc.z : __expf(acc.z) - 1.f;
    acc.w = acc.w > 0.f ? acc.w : __expf(acc.w) - 1.f;
  }
  *reinterpret_cast<float4*>(Out + (size_t)node*HIDDIM + 4*lane) = acc;
}

// ---------------- launch ----------------
extern "C" void kernel_launch(void* const* d_in, const int* in_sizes, int n_in,
                              void* d_out, int out_size, void* d_ws, size_t ws_size,
                              hipStream_t stream)
{
  const float* x    = (const float*)d_in[0];
  const int*   ei   = (const int*)  d_in[1];
  const float* W1   = (const float*)d_in[2];
  const float* aS1  = (const float*)d_in[3];
  const float* aD1  = (const float*)d_in[4];
  const float* b1   = (const float*)d_in[5];
  const float* W2   = (const float*)d_in[6];
  const float* aS2  = (const float*)d_in[7];
  const float* aD2  = (const float*)d_in[8];
  const float* b2   = (const float*)d_in[9];
  float* out = (float*)d_out;

  char* ws = (char*)d_ws;
  size_t off = 0;
  auto alloc = [&](size_t bytes){ void* p = ws + off; off += (bytes + 255) & ~255ull; return p; };
  __half* hbuf  = (__half*)alloc((size_t)NNODES*HIDDIM*sizeof(__half)); // 25.6 MB
  __half* p16   = (__half*)alloc((size_t)4*EN*sizeof(__half));          // 6.8 MB
  float* as1    = (float*)alloc((size_t)NNODES*4*sizeof(float));
  float* ad1    = (float*)alloc((size_t)NNODES*4*sizeof(float));
  float* as2    = (float*)alloc((size_t)NNODES*sizeof(float));
  float* ad2    = (float*)alloc((size_t)NNODES*sizeof(float));
  unsigned short* W1hi = (unsigned short*)alloc((size_t)128*HIDDIM*sizeof(short));
  unsigned short* W1lo = (unsigned short*)alloc((size_t)128*HIDDIM*sizeof(short));
  unsigned short* W2hi = (unsigned short*)alloc((size_t)256*HIDDIM*sizeof(short));
  unsigned short* W2lo = (unsigned short*)alloc((size_t)256*HIDDIM*sizeof(short));
  int*   counts = (int*)alloc((size_t)NNODES*sizeof(int));
  int*   offs   = (int*)alloc((size_t)(NNODES+1)*sizeof(int));
  int*   cursor = (int*)alloc((size_t)NNODES*sizeof(int));
  int*   bsum   = (int*)alloc(64*sizeof(int));
  int*   boff   = (int*)alloc(64*sizeof(int));
  int*   esrc   = (int*)alloc((size_t)EN*sizeof(int));

  const int nscan = (NNODES + SCAN_CHUNK - 1)/SCAN_CHUNK;   // 25

  // CSR by dst
  k_init_counts<<<(NNODES+255)/256, 256, 0, stream>>>(counts, NNODES);
  k_count     <<<(NEDGES+255)/256, 256, 0, stream>>>(ei, counts, NEDGES);
  k_scan_a    <<<nscan, 256, 0, stream>>>(counts, bsum, NNODES);
  k_scan_b    <<<1, 64, 0, stream>>>(bsum, boff, offs, nscan, NNODES);
  k_scan_c    <<<nscan, 256, 0, stream>>>(counts, boff, offs, cursor, NNODES);
  k_scatter   <<<(EN+255)/256, 256, 0, stream>>>(ei, cursor, esrc, NEDGES, NNODES);

  // weight splits
  k_splitW<<<(128*HIDDIM+255)/256, 256, 0, stream>>>(W1, W1hi, W1lo, 128);
  k_splitW<<<(256*HIDDIM+255)/256, 256, 0, stream>>>(W2, W2hi, W2lo, 256);

  const int gemm_grid = (NNODES + 63)/64;   // 782
  const int node_grid = (NNODES + 3)/4;     // 12500

  // layer 1
  k_gemm_mfma<128,4><<<gemm_grid, 256, 0, stream>>>(x, W1hi, W1lo, aS1, aD1, hbuf, as1, ad1, NNODES);
  k_prep<4><<<node_grid, 256, 0, stream>>>(as1, ad1, offs, esrc, p16, NNODES);
  k_agg3<4,true><<<node_grid, 256, 0, stream>>>(hbuf, p16, offs, esrc, b1, out, NNODES);

  // layer 2
  k_gemm_mfma<256,1><<<gemm_grid, 256, 0, stream>>>(out, W2hi, W2lo, aS2, aD2, hbuf, as2, ad2, NNODES);
  k_prep<1><<<node_grid, 256, 0, stream>>>(as2, ad2, offs, esrc, p16, NNODES);
  k_agg3<1,false><<<node_grid, 256, 0, stream>>>(hbuf, p16, offs, esrc, b2, out, NNODES);
}